// Round 4
// baseline (301.341 us; speedup 1.0000x reference)
//
#include <hip/hip_runtime.h>
#include <hip/hip_bf16.h>

#define NUM_EXPERTS 8
#define MODEL_DIM 1024
#define INTER_DIM 4096
#define BM 128
#define BN 128
#define BK 32
#define LSTR 40  // LDS row stride in shorts (80 B): 2-way max bank aliasing (free)

typedef __attribute__((ext_vector_type(8))) short short8;
typedef __attribute__((ext_vector_type(8))) unsigned short ushort8;
typedef __attribute__((ext_vector_type(4))) float floatx4;

__device__ __forceinline__ unsigned short f2b(float f) {
  union { float f; unsigned int u; } v; v.f = f;
  unsigned int r = v.u + 0x7fffu + ((v.u >> 16) & 1u);
  return (unsigned short)(r >> 16);
}

// ---------------- router: top-2 expert ids per token ----------------
__global__ __launch_bounds__(64) void router_kernel(const float* __restrict__ x,
                                                    const float* __restrict__ gw,
                                                    int* __restrict__ eids, int T) {
  int t = blockIdx.x;
  int lane = threadIdx.x;
  float acc[NUM_EXPERTS];
#pragma unroll
  for (int e = 0; e < NUM_EXPERTS; ++e) acc[e] = 0.f;
  const float* xr = x + (size_t)t * MODEL_DIM;
#pragma unroll 4
  for (int i = lane; i < MODEL_DIM; i += 64) {
    float xv = xr[i];
#pragma unroll
    for (int e = 0; e < NUM_EXPERTS; ++e) acc[e] += xv * gw[e * MODEL_DIM + i];
  }
#pragma unroll
  for (int e = 0; e < NUM_EXPERTS; ++e) {
    float v = acc[e];
#pragma unroll
    for (int off = 32; off > 0; off >>= 1) v += __shfl_xor(v, off);
    acc[e] = v;
  }
  if (lane == 0) {
    int e0 = 0; float b0 = acc[0];
#pragma unroll
    for (int e = 1; e < NUM_EXPERTS; ++e) if (acc[e] > b0) { b0 = acc[e]; e0 = e; }
    int e1 = -1; float b1 = -3.4e38f;
#pragma unroll
    for (int e = 0; e < NUM_EXPERTS; ++e) if (e != e0 && acc[e] > b1) { b1 = acc[e]; e1 = e; }
    eids[t] = e0;
    eids[T + t] = e1;
  }
}

__global__ void hist_kernel(const int* __restrict__ eids, int* __restrict__ counts, int total) {
  int i = blockIdx.x * blockDim.x + threadIdx.x;
  if (i < total) atomicAdd(&counts[eids[i]], 1);
}

__global__ void offsets_kernel(const int* __restrict__ counts, int* __restrict__ offsets,
                               int* __restrict__ cursor) {
  if (threadIdx.x == 0 && blockIdx.x == 0) {
    int s = 0;
    for (int e = 0; e < NUM_EXPERTS; ++e) { offsets[e] = s; cursor[e] = s; s += counts[e]; }
    offsets[NUM_EXPERTS] = s;
  }
}

__global__ void scatter_kernel(const int* __restrict__ eids, int* __restrict__ cursor,
                               int* __restrict__ token_list, int T) {
  int i = blockIdx.x * blockDim.x + threadIdx.x;
  if (i < 2 * T) {
    int e = eids[i];
    int pos = atomicAdd(&cursor[e], 1);
    int t = (i >= T) ? (i - T) : i;
    token_list[pos] = t;
  }
}

// ---- prefetch register sets (named scalars only — spill-proof) ----
#define DECL_PF(S)                                     \
  float4 xa0##S, xa1##S, xa2##S, xa3##S;               \
  uint4 ha0##S, ha1##S;                                \
  float w##S##_0, w##S##_1, w##S##_2, w##S##_3,        \
        w##S##_4, w##S##_5, w##S##_6, w##S##_7,        \
        w##S##_8, w##S##_9, w##S##_10, w##S##_11,      \
        w##S##_12, w##S##_13, w##S##_14, w##S##_15;

#define PF_LOAD_A_UP(S, kk)                            \
  xa0##S = *(const float4*)(aptr_f + (kk));            \
  xa1##S = *(const float4*)(aptr_f + (kk) + 4);        \
  xa2##S = *(const float4*)(aptr_f + (kk) + 8);        \
  xa3##S = *(const float4*)(aptr_f + (kk) + 12);

#define PF_LOAD_A_DN(S, kk)                            \
  ha0##S = *(const uint4*)(aptr_h + (kk));             \
  ha1##S = *(const uint4*)(aptr_h + (kk) + 8);

#define PF_LOAD_B(S, kk) {                             \
  const float* bp = bptr + (size_t)((kk) + bks) * N;   \
  w##S##_0  = bp[0];              w##S##_1  = bp[(size_t)1 * N];  \
  w##S##_2  = bp[(size_t)2 * N];  w##S##_3  = bp[(size_t)3 * N];  \
  w##S##_4  = bp[(size_t)4 * N];  w##S##_5  = bp[(size_t)5 * N];  \
  w##S##_6  = bp[(size_t)6 * N];  w##S##_7  = bp[(size_t)7 * N];  \
  w##S##_8  = bp[(size_t)8 * N];  w##S##_9  = bp[(size_t)9 * N];  \
  w##S##_10 = bp[(size_t)10 * N]; w##S##_11 = bp[(size_t)11 * N]; \
  w##S##_12 = bp[(size_t)12 * N]; w##S##_13 = bp[(size_t)13 * N]; \
  w##S##_14 = bp[(size_t)14 * N]; w##S##_15 = bp[(size_t)15 * N]; \
}

#define PF_LOAD(S, kk) {                               \
  if constexpr (UP) { PF_LOAD_A_UP(S, (kk)) }          \
  else              { PF_LOAD_A_DN(S, (kk)) }          \
  PF_LOAD_B(S, (kk))                                   \
}

#define PF_STORE_A_UP(S, buf) {                                               \
  ushort8 s0, s1;                                                             \
  s0[0]=f2b(xa0##S.x); s0[1]=f2b(xa0##S.y); s0[2]=f2b(xa0##S.z); s0[3]=f2b(xa0##S.w); \
  s0[4]=f2b(xa1##S.x); s0[5]=f2b(xa1##S.y); s0[6]=f2b(xa1##S.z); s0[7]=f2b(xa1##S.w); \
  s1[0]=f2b(xa2##S.x); s1[1]=f2b(xa2##S.y); s1[2]=f2b(xa2##S.z); s1[3]=f2b(xa2##S.w); \
  s1[4]=f2b(xa3##S.x); s1[5]=f2b(xa3##S.y); s1[6]=f2b(xa3##S.z); s1[7]=f2b(xa3##S.w); \
  *(ushort8*)(&(buf)[ar * LSTR + akh]) = s0;                                  \
  *(ushort8*)(&(buf)[ar * LSTR + akh + 8]) = s1;                              \
}

#define PF_STORE_A_DN(S, buf) {                        \
  *(uint4*)(&(buf)[ar * LSTR + akh]) = ha0##S;         \
  *(uint4*)(&(buf)[ar * LSTR + akh + 8]) = ha1##S;     \
}

#define PF_STORE_B(S, buf) {                                                  \
  ushort8 s0, s1;                                                             \
  s0[0]=f2b(w##S##_0);  s0[1]=f2b(w##S##_1);  s0[2]=f2b(w##S##_2);  s0[3]=f2b(w##S##_3);  \
  s0[4]=f2b(w##S##_4);  s0[5]=f2b(w##S##_5);  s0[6]=f2b(w##S##_6);  s0[7]=f2b(w##S##_7);  \
  s1[0]=f2b(w##S##_8);  s1[1]=f2b(w##S##_9);  s1[2]=f2b(w##S##_10); s1[3]=f2b(w##S##_11); \
  s1[4]=f2b(w##S##_12); s1[5]=f2b(w##S##_13); s1[6]=f2b(w##S##_14); s1[7]=f2b(w##S##_15); \
  *(ushort8*)(&(buf)[bn * LSTR + bks]) = s0;                                  \
  *(ushort8*)(&(buf)[bn * LSTR + bks + 8]) = s1;                              \
}

#define PF_STORE(S, bufA, bufB) {                      \
  if constexpr (UP) { PF_STORE_A_UP(S, bufA) }         \
  else              { PF_STORE_A_DN(S, bufA) }         \
  PF_STORE_B(S, bufB)                                  \
}

#define COMPUTE(bufA, bufB) {                                                 \
  const unsigned short* rA = (bufA);                                          \
  const unsigned short* rB = (bufB);                                          \
  short8 a[4], b[4];                                                          \
  _Pragma("unroll")                                                           \
  for (int i = 0; i < 4; ++i)                                                 \
    a[i] = *(const short8*)(&rA[(wm * 64 + i * 16 + fr) * LSTR + koff]);      \
  _Pragma("unroll")                                                           \
  for (int j = 0; j < 4; ++j)                                                 \
    b[j] = *(const short8*)(&rB[(wn * 64 + j * 16 + fr) * LSTR + koff]);      \
  _Pragma("unroll")                                                           \
  for (int i = 0; i < 4; ++i)                                                 \
    _Pragma("unroll")                                                         \
    for (int j = 0; j < 4; ++j)                                               \
      acc[i][j] = __builtin_amdgcn_mfma_f32_16x16x32_bf16(a[i], b[j], acc[i][j], 0, 0, 0); \
}

// ---------------- grouped GEMM, 128x128 tile, depth-2 reg prefetch + LDS dbuf ----
// UP:   h[row][n]  = bf16(x[token[row]]) @ bf16(W_up[e])    (fp32 in, bf16 out)
// DOWN: out[token] += h[row] @ bf16(W_down[e])              (bf16 in, atomic fp32 out), split-K=4
template <bool UP>
__global__ __launch_bounds__(256, 2) void moe_gemm(
    const float* __restrict__ W,
    const float* __restrict__ X,
    const unsigned short* __restrict__ H,
    unsigned short* __restrict__ Hout,
    float* __restrict__ Out,
    const int* __restrict__ offsets,
    const int* __restrict__ token_list) {
  constexpr int K = UP ? MODEL_DIM : INTER_DIM;
  constexpr int N = UP ? INTER_DIM : MODEL_DIM;
  constexpr int KCH = 1024;          // per-block K chunk (UP: full K; DOWN: K/4)
  constexpr int NSTEP = KCH / BK;    // 32 (even)

  const int zz = blockIdx.z;
  const int e = UP ? zz : (zz >> 2);
  const int kbeg = UP ? 0 : (zz & 3) * KCH;

  const int off = offsets[e];
  const int cnt = offsets[e + 1] - off;
  const int m0 = blockIdx.y * BM;
  if (m0 >= cnt) return;
  const int n0 = blockIdx.x * BN;

  __shared__ unsigned short sA[2][BM * LSTR];
  __shared__ unsigned short sB[2][BN * LSTR];

  const int tid = threadIdx.x;
  const int lane = tid & 63;
  const int wave = tid >> 6;
  const int wm = wave >> 1, wn = wave & 1;
  const int koff = (lane >> 4) * 8;
  const int fr = lane & 15;

  // A staging ids: 2 threads per row, 16 k-elems each
  const int ar = tid >> 1;
  const int akh = (tid & 1) * 16;
  const int arow = m0 + ar;
  const int aclamped = off + (arow < cnt ? arow : cnt - 1);
  const float* aptr_f = nullptr;
  const unsigned short* aptr_h = nullptr;
  if constexpr (UP) {
    aptr_f = X + (size_t)token_list[aclamped] * MODEL_DIM + akh;
  } else {
    aptr_h = H + (size_t)aclamped * INTER_DIM + akh;
  }

  // B staging ids: thread -> (n, 16 k-elems); stored transposed sB[n][k]
  const int bn = tid & 127;
  const int bks = (tid >> 7) * 16;
  const float* bptr = W + (size_t)e * K * N + n0 + bn;

  floatx4 acc[4][4];
  const floatx4 zero = {0.f, 0.f, 0.f, 0.f};
#pragma unroll
  for (int i = 0; i < 4; ++i)
#pragma unroll
    for (int j = 0; j < 4; ++j) acc[i][j] = zero;

  DECL_PF(0)
  DECL_PF(1)

  // prologue: two K-steps in flight; stage step 0 into buf 0
  PF_LOAD(0, kbeg)
  PF_LOAD(1, kbeg + BK)
  PF_STORE(0, sA[0], sB[0])
  __syncthreads();

  for (int s = 0; s < NSTEP; s += 2) {
    // even step: compute buf0 (k-step s); issue loads for s+2; stage s+1 -> buf1
    if (s + 2 < NSTEP) { PF_LOAD(0, kbeg + (s + 2) * BK) }
    COMPUTE(sA[0], sB[0])
    PF_STORE(1, sA[1], sB[1])
    __syncthreads();

    // odd step: compute buf1 (k-step s+1); issue loads for s+3; stage s+2 -> buf0
    if (s + 3 < NSTEP) { PF_LOAD(1, kbeg + (s + 3) * BK) }
    COMPUTE(sA[1], sB[1])
    if (s + 2 < NSTEP) {
      PF_STORE(0, sA[0], sB[0])
      __syncthreads();
    }
  }

  // epilogue: C/D layout col=lane&15, row=(lane>>4)*4+j
  const int rbase = wm * 64 + (lane >> 4) * 4;
  const int cbase = wn * 64 + fr;
#pragma unroll
  for (int fm = 0; fm < 4; ++fm) {
#pragma unroll
    for (int fn = 0; fn < 4; ++fn) {
#pragma unroll
      for (int j = 0; j < 4; ++j) {
        const int r = rbase + fm * 16 + j;
        const int c = cbase + fn * 16;
        if (m0 + r < cnt) {
          if constexpr (UP) {
            Hout[(size_t)(off + m0 + r) * INTER_DIM + n0 + c] = f2b(acc[fm][fn][j]);
          } else {
            const int t = token_list[off + m0 + r];
            atomicAdd(&Out[(size_t)t * MODEL_DIM + n0 + c], acc[fm][fn][j]);
          }
        }
      }
    }
  }
}

extern "C" void kernel_launch(void* const* d_in, const int* in_sizes, int n_in,
                              void* d_out, int out_size, void* d_ws, size_t ws_size,
                              hipStream_t stream) {
  const float* x = (const float*)d_in[0];
  const float* gw = (const float*)d_in[1];
  const float* w_up = (const float*)d_in[2];
  const float* w_down = (const float*)d_in[3];
  float* out = (float*)d_out;

  const int T = in_sizes[0] / MODEL_DIM;  // 2048
  const int total = 2 * T;                // 4096 routed rows

  int* ws_i = (int*)d_ws;
  int* eids = ws_i;                 // [total]
  int* counts = ws_i + total;       // [8]
  int* offsets = counts + 8;        // [9]
  int* cursor = offsets + 12;       // [8]
  int* token_list = cursor + 8;     // [total]
  unsigned short* h = (unsigned short*)((char*)d_ws + (256 << 10));  // [total][INTER_DIM] bf16

  hipMemsetAsync(counts, 0, NUM_EXPERTS * sizeof(int), stream);
  hipMemsetAsync(d_out, 0, (size_t)out_size * sizeof(float), stream);

  router_kernel<<<T, 64, 0, stream>>>(x, gw, eids, T);
  hist_kernel<<<(total + 255) / 256, 256, 0, stream>>>(eids, counts, total);
  offsets_kernel<<<1, 64, 0, stream>>>(counts, offsets, cursor);
  scatter_kernel<<<(total + 255) / 256, 256, 0, stream>>>(eids, cursor, token_list, T);

  dim3 gup(INTER_DIM / BN, total / BM, NUM_EXPERTS);
  moe_gemm<true><<<gup, 256, 0, stream>>>(w_up, x, nullptr, h, nullptr, offsets, token_list);
  dim3 gdn(MODEL_DIM / BN, total / BM, NUM_EXPERTS * 4);  // split-K=4 for occupancy
  moe_gemm<false><<<gdn, 256, 0, stream>>>(w_down, nullptr, h, nullptr, out, offsets, token_list);
}